// Round 1
// baseline (68.557 us; speedup 1.0000x reference)
//
#include <hip/hip_runtime.h>
#include <math.h>

#define KCOMP 1024
#define DDIM  6
#define BPTS  16384

#define PTS    64            // points per block (4 MFMA pt-tiles of 16)
#define NWAVE  16            // waves per block; wave w owns comps [w*64, w*64+64)
#define NTPW   4             // n-tiles per wave (4 x 16 = 64 comps)

typedef __attribute__((ext_vector_type(8))) short bf16x8;  // 8 bf16 = 4 VGPRs
typedef __attribute__((ext_vector_type(4))) float f32x4;
typedef __attribute__((ext_vector_type(4))) unsigned int u32x4;

// self-contained bf16 helpers (RNE)
__device__ __forceinline__ unsigned short f32_to_bf16(float f) {
    unsigned int u = __float_as_uint(f);
    u += 0x7fffu + ((u >> 16) & 1u);
    return (unsigned short)(u >> 16);
}
__device__ __forceinline__ float bf16_to_f32(unsigned short h) {
    return __uint_as_float(((unsigned int)h) << 16);
}

// Sum across each row of 16 lanes via DPP rotate-adds (VALU pipe).
__device__ __forceinline__ float row16_sum(float v) {
    int t;
    t = __builtin_amdgcn_update_dpp(0, __float_as_int(v), 0x121, 0xf, 0xf, false); // row_ror:1
    v += __int_as_float(t);
    t = __builtin_amdgcn_update_dpp(0, __float_as_int(v), 0x122, 0xf, 0xf, false); // row_ror:2
    v += __int_as_float(t);
    t = __builtin_amdgcn_update_dpp(0, __float_as_int(v), 0x124, 0xf, 0xf, false); // row_ror:4
    v += __int_as_float(t);
    t = __builtin_amdgcn_update_dpp(0, __float_as_int(v), 0x128, 0xf, 0xf, false); // row_ror:8
    v += __int_as_float(t);
    return v;
}

// ---------------------------------------------------------------------------
// Fused single-dispatch kernel (R7). The R5 two-kernel split cost a second
// dispatch + inter-kernel bubble (~5-10 us) for ~3 us of precompute work.
// Fusion WITHOUT the R6 regression: comp->wave mapping makes W wave-local.
//   wave w consumes comps [w*64, w*64+64) == 64 lanes: lane l runs the
//   Cholesky for comp w*64+l (identical math to the R5 precompute kernel),
//   then the wave redistributes the 32 packed bf16-pair dwords through its
//   PRIVATE 4KB LDS slice (hi pass, then lo pass reusing the same slice;
//   ordering is wave-local s_waitcnt lgkmcnt(0) -- no block barrier).
//   W fragments then sit in 32 VGPRs for the whole MFMA loop (the per-tile
//   global W loads of R5 are gone too).
// Redistribution layout: src lane l=(t*16|n15) packs features as dwords
//   d[p] = bf16(wv[2p]) | bf16(wv[2p+1])<<16   (p=0..15 per split).
//   Dest lane (quad<<4|n15), tile t needs dwords quad*4..quad*4+3 of src
//   slot t*16+n15 -> one ds_read_b128. XOR swizzle key f(s)=((s>>1)&3)<<2
//   (slot-internal, bijective) spreads the stride-64B read across 8 bank
//   groups (2-way residual = free, m136).
// LDS = exactly 64 KB: wred[16][64][16] dwords; fragA (8KB) and partial
//   (4KB) reuse slices 0-2 behind the two __syncthreads (all wave-local
//   redist reads complete before their own barrier arrival).
// VGPR phases are disjoint (Cholesky ~100 live, main loop ~95) -> fits the
//   128-cap of launch_bounds(1024,4) without spilling the main loop.
// ---------------------------------------------------------------------------
__global__ __launch_bounds__(1024, 4) void gmm_fused(
        const float* __restrict__ x,
        const float* __restrict__ means,
        const float* __restrict__ covs,
        const float* __restrict__ weights,
        float* __restrict__ out) {
    const int tid  = threadIdx.x;
    const int lane = tid & 63;
    const int w    = __builtin_amdgcn_readfirstlane(tid >> 6);  // 0..15
    const int quad = lane >> 4;                                  // 0..3
    const int m15  = lane & 15;
    const int pbase = blockIdx.x * PTS;

    __shared__ __attribute__((aligned(16))) char smem[65536];
    unsigned int* wred    = (unsigned int*)smem;     // [16 waves][64 slots][16 dw]
    bf16x8*       fragA   = (bf16x8*)smem;           // [8][64]  (phase 2)
    float*        partial = (float*)(smem + 8192);   // [16][64] (phase 4)

    // ---- producer A-fragment values (regs only; LDS write deferred) ----
    bf16x8 frag = {};
    if (w < 8) {
        const int pt    = w & 3;
        const int split = w >> 2;            // 0 = hi, 1 = lo
        float v[6];
        const float* xp = x + (pbase + pt * 16 + m15) * 6;
        #pragma unroll
        for (int i = 0; i < 6; i++) v[i] = xp[i];

        float f[8];
        if (quad == 0) {
            f[0]=v[0]*v[0]; f[1]=v[0]*v[1]; f[2]=v[0]*v[2]; f[3]=v[0]*v[3];
            f[4]=v[0]*v[4]; f[5]=v[0]*v[5]; f[6]=v[1]*v[1]; f[7]=v[1]*v[2];
        } else if (quad == 1) {
            f[0]=v[1]*v[3]; f[1]=v[1]*v[4]; f[2]=v[1]*v[5]; f[3]=v[2]*v[2];
            f[4]=v[2]*v[3]; f[5]=v[2]*v[4]; f[6]=v[2]*v[5]; f[7]=v[3]*v[3];
        } else if (quad == 2) {
            f[0]=v[3]*v[4]; f[1]=v[3]*v[5]; f[2]=v[4]*v[4]; f[3]=v[4]*v[5];
            f[4]=v[5]*v[5]; f[5]=v[0];      f[6]=v[1];      f[7]=v[2];
        } else {
            f[0]=v[3]; f[1]=v[4]; f[2]=v[5]; f[3]=1.0f;
            f[4]=0.0f; f[5]=0.0f; f[6]=0.0f; f[7]=0.0f;
        }

        #pragma unroll
        for (int j = 0; j < 8; j++) {
            unsigned short h = f32_to_bf16(f[j]);
            frag[j] = (split == 0) ? (short)h
                                   : (short)f32_to_bf16(f[j] - bf16_to_f32(h));
        }
    }

    // ---- per-lane precompute for comp k = w*64+lane (same math as R5) ----
    const int k = w * 64 + lane;
    float A[6][6];
    {
        const f32x4* C4 = (const f32x4*)(covs + k * 36);   // k*144 B, 16B aligned
        float cf[36];
        #pragma unroll
        for (int q = 0; q < 9; q++) {
            f32x4 t4 = C4[q];
            #pragma unroll
            for (int e = 0; e < 4; e++) cf[q * 4 + e] = t4[e];
        }
        #pragma unroll
        for (int i = 0; i < 6; i++)
            #pragma unroll
            for (int j = 0; j < 6; j++)
                A[i][j] = cf[i * 6 + j];
    }

    // In-place Cholesky: lower triangle of A becomes L. Track diag product.
    float dprod = 1.0f;
    #pragma unroll
    for (int j = 0; j < 6; j++) {
        float d = A[j][j];
        #pragma unroll
        for (int t = 0; t < 6; t++) if (t < j) d -= A[j][t] * A[j][t];
        float ljj = __builtin_amdgcn_sqrtf(d);
        dprod *= ljj;
        A[j][j] = ljj;
        float inv = __builtin_amdgcn_rcpf(ljj);
        #pragma unroll
        for (int i = 0; i < 6; i++) {
            if (i > j) {
                float s = A[i][j];
                #pragma unroll
                for (int t = 0; t < 6; t++) if (t < j) s -= A[i][t] * A[j][t];
                A[i][j] = s * inv;
            }
        }
    }
    float logdet2 = 2.0f * __builtin_amdgcn_logf(dprod);   // log2(det Sigma)

    // Li = L^{-1} (lower)
    float Li[6][6];
    #pragma unroll
    for (int j = 0; j < 6; j++) {
        Li[j][j] = __builtin_amdgcn_rcpf(A[j][j]);
        #pragma unroll
        for (int i = 0; i < 6; i++) {
            if (i > j) {
                float s = 0.0f;
                #pragma unroll
                for (int t = 0; t < 6; t++) if (t >= j && t < i) s += A[i][t] * Li[t][j];
                Li[i][j] = -s * __builtin_amdgcn_rcpf(A[i][i]);
            }
        }
    }

    // P = Li^T Li -> overwrite A
    #pragma unroll
    for (int i = 0; i < 6; i++) {
        #pragma unroll
        for (int j = 0; j < 6; j++) {
            if (j >= i) {
                float s = 0.0f;
                int lo = (i > j) ? i : j;
                #pragma unroll
                for (int t = 0; t < 6; t++) if (t >= lo) s += Li[t][i] * Li[t][j];
                A[i][j] = s;
                A[j][i] = s;
            }
        }
    }

    const float* mu = means + k * 6;
    float m[6];
    #pragma unroll
    for (int i = 0; i < 6; i++) m[i] = mu[i];

    float b[6];
    float muPmu = 0.0f;
    #pragma unroll
    for (int i = 0; i < 6; i++) {
        float s = 0.0f;
        #pragma unroll
        for (int j = 0; j < 6; j++) s += A[i][j] * m[j];
        b[i] = s;
        muPmu += s * m[i];
    }

    const float LOG2_2PI = 2.6514961294723187f;   // log2(2*pi)
    const float LOG2E    = 1.4426950408889634f;
    float c2 = __builtin_amdgcn_logf(weights[k])
             - 0.5f * (6.0f * LOG2_2PI + logdet2)
             - 0.5f * LOG2E * muPmu;

    float wv[32];
    {
        int t = 0;
        #pragma unroll
        for (int i = 0; i < 6; i++)
            #pragma unroll
            for (int j = 0; j < 6; j++)
                if (j >= i) wv[t++] = LOG2E * ((i == j) ? -0.5f * A[i][j] : -A[i][j]);
        #pragma unroll
        for (int i = 0; i < 6; i++) wv[t++] = LOG2E * b[i];
        wv[27] = c2;
        wv[28] = 0.0f; wv[29] = 0.0f; wv[30] = 0.0f; wv[31] = 0.0f;
    }

    // pack split-bf16 pairs: dword p = bf16(wv[2p]) | bf16(wv[2p+1])<<16
    unsigned int hi_d[16], lo_d[16];
    #pragma unroll
    for (int p = 0; p < 16; p++) {
        unsigned short h0 = f32_to_bf16(wv[2 * p]);
        unsigned short h1 = f32_to_bf16(wv[2 * p + 1]);
        hi_d[p] = (unsigned int)h0 | ((unsigned int)h1 << 16);
        unsigned short l0 = f32_to_bf16(wv[2 * p]     - bf16_to_f32(h0));
        unsigned short l1 = f32_to_bf16(wv[2 * p + 1] - bf16_to_f32(h1));
        lo_d[p] = (unsigned int)l0 | ((unsigned int)l1 << 16);
    }

    // ---- wave-local redistribution through this wave's private 4KB slice ----
    unsigned int* wslot = wred + w * 1024;          // 64 slots x 16 dwords
    const int fw = ((lane >> 1) & 3) << 2;          // write swizzle key (this lane as src)
    const int fr = ((m15 >> 1) & 3) << 2;           // read swizzle key (= f(src slot))
    bf16x8 bh[4], bl[4];

    // hi pass
    #pragma unroll
    for (int c = 0; c < 4; c++) {
        u32x4 d = { hi_d[c * 4 + 0], hi_d[c * 4 + 1], hi_d[c * 4 + 2], hi_d[c * 4 + 3] };
        *(u32x4*)&wslot[lane * 16 + ((c * 4) ^ fw)] = d;
    }
    asm volatile("s_waitcnt lgkmcnt(0)" ::: "memory");
    #pragma unroll
    for (int t = 0; t < 4; t++) {
        const int s = t * 16 + m15;
        bh[t] = *(const bf16x8*)&wslot[s * 16 + ((quad * 4) ^ fr)];
    }
    asm volatile("s_waitcnt lgkmcnt(0)" ::: "memory");
    // lo pass (reuses the same slice; reads above are drained)
    #pragma unroll
    for (int c = 0; c < 4; c++) {
        u32x4 d = { lo_d[c * 4 + 0], lo_d[c * 4 + 1], lo_d[c * 4 + 2], lo_d[c * 4 + 3] };
        *(u32x4*)&wslot[lane * 16 + ((c * 4) ^ fw)] = d;
    }
    asm volatile("s_waitcnt lgkmcnt(0)" ::: "memory");
    #pragma unroll
    for (int t = 0; t < 4; t++) {
        const int s = t * 16 + m15;
        bl[t] = *(const bf16x8*)&wslot[s * 16 + ((quad * 4) ^ fr)];
    }

    // ---- A fragments through LDS (region reuse is barrier-protected) ----
    __syncthreads();                          // all wave-local redist reads done
    if (w < 8) fragA[w * 64 + lane] = frag;
    __syncthreads();

    bf16x8 Ah[4], Al[4];
    #pragma unroll
    for (int pt = 0; pt < 4; pt++) {
        Ah[pt] = fragA[pt * 64 + lane];
        Al[pt] = fragA[(4 + pt) * 64 + lane];
    }

    // ---- MFMA loop: all operands register-resident ----
    float esum[4][4];
    #pragma unroll
    for (int pt = 0; pt < 4; pt++)
        #pragma unroll
        for (int r = 0; r < 4; r++) esum[pt][r] = 0.0f;

    #pragma unroll
    for (int t = 0; t < NTPW; t++) {
        #pragma unroll
        for (int pt = 0; pt < 4; pt++) {
            f32x4 c = {0.0f, 0.0f, 0.0f, 0.0f};
            c = __builtin_amdgcn_mfma_f32_16x16x32_bf16(Ah[pt], bh[t], c, 0, 0, 0);
            c = __builtin_amdgcn_mfma_f32_16x16x32_bf16(Al[pt], bh[t], c, 0, 0, 0);
            c = __builtin_amdgcn_mfma_f32_16x16x32_bf16(Ah[pt], bl[t], c, 0, 0, 0);
            #pragma unroll
            for (int r = 0; r < 4; r++)
                esum[pt][r] += __builtin_amdgcn_exp2f(c[r]);
        }
    }

    // ---- reduce over the 16 comp-lanes (DPP row_ror rotate-adds) ----
    #pragma unroll
    for (int pt = 0; pt < 4; pt++)
        #pragma unroll
        for (int r = 0; r < 4; r++)
            esum[pt][r] = row16_sum(esum[pt][r]);

    if (m15 == 0) {
        #pragma unroll
        for (int pt = 0; pt < 4; pt++)
            #pragma unroll
            for (int r = 0; r < 4; r++)
                partial[w * PTS + pt * 16 + quad * 4 + r] = esum[pt][r];
    }
    __syncthreads();

    if (tid < PTS) {
        float S = 0.0f;
        #pragma unroll
        for (int c = 0; c < NWAVE; c++) S += partial[c * PTS + tid];
        const float LN2 = 0.6931471805599453f;
        out[pbase + tid] = LN2 * __builtin_amdgcn_logf(S);  // v_log_f32 = log2
    }
}

extern "C" void kernel_launch(void* const* d_in, const int* in_sizes, int n_in,
                              void* d_out, int out_size, void* d_ws, size_t ws_size,
                              hipStream_t stream) {
    const float* x       = (const float*)d_in[0];  // [B, 6]
    const float* means   = (const float*)d_in[1];  // [K, 6]
    const float* covs    = (const float*)d_in[2];  // [K, 6, 6]
    const float* weights = (const float*)d_in[3];  // [K]
    float* out = (float*)d_out;                    // [B]

    (void)d_ws; (void)ws_size;                     // workspace no longer needed

    gmm_fused<<<BPTS / PTS, 1024, 0, stream>>>(x, means, covs, weights, out);
}